// Round 8
// baseline (277.896 us; speedup 1.0000x reference)
//
#include <hip/hip_runtime.h>
#include <cstdint>

typedef __attribute__((ext_vector_type(8))) short short8;
typedef __attribute__((ext_vector_type(4))) float floatx4;

#define TWO_PI 6.283185307179586f

__device__ __forceinline__ unsigned short f2bf(float f) {
  union { float f; uint32_t u; } c; c.f = f;
  uint32_t u = c.u;
  u += 0x7FFFu + ((u >> 16) & 1u);   // RNE
  return (unsigned short)(u >> 16);
}
__device__ __forceinline__ uint32_t packbf(float re, float im) {
  return (uint32_t)f2bf(re) | ((uint32_t)f2bf(im) << 16);
}

// ---------------------------------------------------------------------------
// Four-step DFT convolution, N = 65536 = 256 x 256, t = c + 256 r, k = k1+256k2.
// z_s = x[2s] + i x[2s+1].  All stages are real bf16 MFMA GEMMs (2x2 rotation
// embedding), with ALL matrices stored MFMA FRAGMENT-MAJOR:
//   frag(M16, kc, ks): 64 lanes x 16 B contiguous;
//   lane(qlo,qhi) holds  Mrow = M16*16+qlo,  k-shorts kc*64+ks*32+qhi*8 ..+8
//   (= u32 cols kc*32+ks*16+qhi*4 ..+4 for packed data).
// K-loops are pure register GEMMs: coalesced global_load_dwordx4 -> MFMA.
// Stages 2+3 are FUSED: P fragments live in 64 KB LDS (frag-major => the
// ds_read_b128 at base+lane*16 is inherently bank-conflict-free), ONE barrier.
// Fragment values and MFMA order identical to the staged path -> bit-identical.
// ---------------------------------------------------------------------------

// prep: [0,512) A1f; [512,1536) A2f; [1536,2560) A3f; [2560,3072) A4f;
// [3072,4096) x -> Zp frag-major; [4096,4352) Gw; [4352,4608) Tw.
__global__ __launch_bounds__(256) void prep_all(
    const float* __restrict__ x, const float* __restrict__ filt,
    unsigned short* __restrict__ A1, unsigned short* __restrict__ A2,
    unsigned short* __restrict__ A3, unsigned short* __restrict__ A4,
    uint32_t* __restrict__ Zp, float2* __restrict__ Gw,
    float2* __restrict__ Tw) {
  __shared__ float2 roots[256];
  const int bid = blockIdx.x;
  const int tid = threadIdx.x;
  const float w256 = TWO_PI / 256.0f;
  if (bid < 3072) {
    // fragment-major position -> (row, col) -> original twiddle value
    if (bid < 512) {                          // A1 [512 rows=2k1+d][256 k=2r+e]
      int j = bid * 256 + tid;
      int jj = j & 7, ln = (j >> 3) & 63, ks = (j >> 9) & 1;
      int t = j >> 10, M16 = t & 31, kc = t >> 5;
      int row = M16 * 16 + (ln & 15);
      int col = kc * 64 + ks * 32 + (ln >> 4) * 8 + jj;
      int k1 = row >> 1, d = row & 1, r = col >> 1, e = col & 1;
      float th = (float)((k1 * r) & 255) * w256;
      float sn, cs; __sincosf(th, &sn, &cs);
      A1[j] = f2bf(d == 0 ? (e == 0 ? cs : sn) : (e == 0 ? -sn : cs));
    } else if (bid < 1536) {                  // A2 [512 rows=2k2+d][512 k=2c+e], E-
      int j = (bid - 512) * 256 + tid;
      int jj = j & 7, ln = (j >> 3) & 63, ks = (j >> 9) & 1;
      int t = j >> 10, M16 = t & 31, kc = t >> 5;
      int row = M16 * 16 + (ln & 15);
      int col = kc * 64 + ks * 32 + (ln >> 4) * 8 + jj;
      int k2 = row >> 1, d = row & 1, cc = col >> 1, e = col & 1;
      float th = (float)((k2 * cc) & 255) * w256;
      float sn, cs; __sincosf(th, &sn, &cs);
      A2[j] = f2bf(d == 0 ? (e == 0 ? cs : sn) : (e == 0 ? -sn : cs));
    } else if (bid < 2560) {                  // A3 [512 rows=2c+d][512 k=2k2+e], E+
      int j = (bid - 1536) * 256 + tid;
      int jj = j & 7, ln = (j >> 3) & 63, ks = (j >> 9) & 1;
      int t = j >> 10, M16 = t & 31, kc = t >> 5;
      int row = M16 * 16 + (ln & 15);
      int col = kc * 64 + ks * 32 + (ln >> 4) * 8 + jj;
      int cc = row >> 1, d = row & 1, k2 = col >> 1, e = col & 1;
      float th = (float)((k2 * cc) & 255) * w256;
      float sn, cs; __sincosf(th, &sn, &cs);
      A3[j] = f2bf(d == 0 ? (e == 0 ? cs : -sn) : (e == 0 ? sn : cs));
    } else {                                  // A4 [256 rows=2r+d][512 k=2k1+e], E+
      int j = (bid - 2560) * 256 + tid;
      int jj = j & 7, ln = (j >> 3) & 63, ks = (j >> 9) & 1;
      int t = j >> 10, M16 = t & 15, kc = t >> 4;
      int row = M16 * 16 + (ln & 15);
      int col = kc * 64 + ks * 32 + (ln >> 4) * 8 + jj;
      int r = row >> 1, d = row & 1, k1 = col >> 1, e = col & 1;
      float th = (float)((k1 * r) & 255) * w256;
      float sn, cs; __sincosf(th, &sn, &cs);
      A4[j] = f2bf(d == 0 ? (e == 0 ? cs : -sn) : (e == 0 ? sn : cs));
    }
  } else if (bid < 4096) {                    // Zp frag-major: per s, rows=c(256),
    int b2 = bid - 3072;                      //   u32-cols=r(128), kc in [0,4)
    int s = b2 >> 3, rq = b2 & 7;
    const float* x0 = x + (size_t)(2 * s) * 32768;
    const float* x1 = x0 + 32768;
    uint32_t v[16];
    #pragma unroll
    for (int rr = 0; rr < 16; ++rr) {
      int t = tid + 256 * (rq * 16 + rr);
      v[rr] = (uint32_t)f2bf(x0[t]) | ((uint32_t)f2bf(x1[t]) << 16);
    }
    const int kc = rq >> 1, ks = rq & 1;
    uint32_t* dst = Zp + (size_t)s * 32768 +
                    ((kc * 16 + (tid >> 4)) * 2 + ks) * 256 + (tid & 15) * 4;
    #pragma unroll
    for (int q = 0; q < 4; ++q)
      *(uint4*)(dst + q * 64) = make_uint4(v[4*q], v[4*q+1], v[4*q+2], v[4*q+3]);
  } else if (bid < 4352) {                    // Gw[k1][c], fp32, root-table loop
    int k1 = bid - 4096, c = tid;
    { float sn, cs; __sincosf((float)tid * w256, &sn, &cs);
      roots[tid] = make_float2(cs, sn); }
    __syncthreads();
    float ar = 0.f, ai = 0.f;
    for (int r = 0; r < 128; ++r) {
      float v = filt[c + 256 * r];
      float2 wv = roots[(k1 * r) & 255];
      ar += v * wv.x; ai -= v * wv.y;
    }
    float th = (float)((k1 * c) & 65535) * (TWO_PI / 65536.0f);
    float sn, cs; __sincosf(th, &sn, &cs);
    Gw[(k1 << 8) + c] = make_float2(ar * cs + ai * sn, ai * cs - ar * sn);
  } else {                                    // Tw[k1][c] = (cos, sin) k1*c/65536
    int k1 = bid - 4352, c = tid;
    float th = (float)((k1 * c) & 65535) * (TWO_PI / 65536.0f);
    float sn, cs; __sincosf(th, &sn, &cs);
    Tw[(k1 << 8) + c] = make_float2(cs, sn);
  }
}

// WtT[k2][k1] = sum_c Gw[k1][c] E-(k2 c/256)   (fp32, TRANSPOSED)
__global__ __launch_bounds__(256) void prep_wb(const float2* __restrict__ Gw,
                                               float2* __restrict__ WtT) {
  __shared__ float2 roots[256];
  int k1 = blockIdx.x, k2 = threadIdx.x;
  { float sn, cs; __sincosf((float)k2 * (TWO_PI / 256.0f), &sn, &cs);
    roots[k2] = make_float2(cs, sn); }
  __syncthreads();
  float ar = 0.f, ai = 0.f;
  for (int c = 0; c < 256; ++c) {
    float2 g = Gw[(k1 << 8) + c];
    float2 wv = roots[(k2 * c) & 255];
    ar += g.x * wv.x + g.y * wv.y;
    ai += g.y * wv.x - g.x * wv.y;
  }
  WtT[(k2 << 8) + k1] = make_float2(ar, ai);
}

// Register-GEMM DFT stage (stages 1 and 4).  Tile 128x128, 4 waves, acc[4][4].
// MODE 1: *Tw(E-) -> G2f (LDS transpose to frag-major).  MODE 4: y directly.
template <int MODE, int KC, int MD16>
__global__ __launch_bounds__(256, 2) void dft_stageR(
    const unsigned short* __restrict__ Af,
    const uint32_t* __restrict__ Bf,
    uint32_t* __restrict__ outp,
    float* __restrict__ yout,
    const float2* __restrict__ tab) {
  __shared__ uint32_t Tr[(MODE == 4) ? 64 : 8704];  // transpose buf (<=34.8 KB)

  const int mt = blockIdx.x >> 8;
  const int nt = blockIdx.x & 255;
  const int m0 = mt * 128, n0 = nt * 128;
  const int s = n0 >> 8;                      // batch-pair index
  const int nlow = n0 & 255;                  // c- or k1- offset within s

  const int tid = threadIdx.x;
  const int w = tid >> 6, lane = tid & 63;
  const int qlo = lane & 15, qhi = lane >> 4;
  const int wr = w >> 1, wc = w & 1;

  floatx4 acc[4][4];
  #pragma unroll
  for (int i = 0; i < 4; ++i)
    #pragma unroll
    for (int j = 0; j < 4; ++j) acc[i][j] = (floatx4){0.f, 0.f, 0.f, 0.f};

  const uint32_t* Bp = Bf + (size_t)s * (KC * 8192);
  const int m16b = (m0 >> 4) + wr * 4;
  const int n16b = (nlow >> 4) + wc * 4;

  #pragma unroll
  for (int kc = 0; kc < KC; ++kc) {
    #pragma unroll
    for (int ks = 0; ks < 2; ++ks) {
      short8 a[4], b[4];
      #pragma unroll
      for (int im = 0; im < 4; ++im)
        a[im] = *(const short8*)(Af +
            (size_t)(((kc * MD16 + m16b + im) * 2 + ks) * 512 + lane * 8));
      #pragma unroll
      for (int in = 0; in < 4; ++in)
        b[in] = *(const short8*)(Bp +
            (((kc * 16 + n16b + in) * 2 + ks) * 256 + lane * 4));
      #pragma unroll
      for (int im = 0; im < 4; ++im)
        #pragma unroll
        for (int in = 0; in < 4; ++in)
          acc[im][in] = __builtin_amdgcn_mfma_f32_16x16x32_bf16(
              a[im], b[in], acc[im][in], 0, 0, 0);
    }
  }

  if constexpr (MODE == 1) {                  // -> G2f rows=k1, u32-cols=c
    #pragma unroll
    for (int im = 0; im < 4; ++im) {
      const int mloc = wr * 32 + im * 8 + qhi * 2;
      #pragma unroll
      for (int in = 0; in < 4; ++in) {
        const int nloc = wc * 64 + in * 16 + qlo;
        const int c = nlow + nloc;
        #pragma unroll
        for (int pp = 0; pp < 2; ++pp) {
          const int k1loc = mloc + pp;
          const int k1 = (m0 >> 1) + k1loc;
          float re = acc[im][in][2*pp], iv = acc[im][in][2*pp+1];
          float2 tw = tab[(k1 << 8) + c];
          float r2 = re * tw.x + iv * tw.y, i2 = iv * tw.x - re * tw.y;
          Tr[k1loc * 132 + nloc] = packbf(r2, i2);
        }
      }
    }
    __syncthreads();
    #pragma unroll
    for (int p = 0; p < 8; ++p) {
      const int sb = p * 4 + w;
      const int kcL = sb >> 3, N16l = (sb >> 1) & 3, ksb = sb & 1;
      uint4 v = *(const uint4*)&Tr[(N16l*16 + qlo) * 132 + kcL*32 + ksb*16 + qhi*4];
      const int kcg = (nlow >> 5) + kcL, N16g = (m0 >> 5) + N16l;
      *(uint4*)&outp[(size_t)s * 65536 +
                     (size_t)(((kcg * 16 + N16g) * 2 + ksb) * 256 + lane * 4)] = v;
    }
  } else {                                    // MODE 4: final y
    #pragma unroll
    for (int im = 0; im < 4; ++im) {
      const int mloc = wr * 32 + im * 8 + qhi * 2;
      #pragma unroll
      for (int in = 0; in < 4; ++in) {
        const int nloc = wc * 64 + in * 16 + qlo;
        const int cloc = nlow + nloc;
        #pragma unroll
        for (int pp = 0; pp < 2; ++pp) {
          const int mC = (m0 >> 1) + mloc + pp;
          float re = acc[im][in][2*pp], iv = acc[im][in][2*pp+1];
          const float sc = 1.0f / 65536.0f;
          float* y0 = yout + ((size_t)s << 16) + (mC << 8) + cloc;
          y0[0] = re * sc;        // y[2s][c+256r]
          y0[32768] = iv * sc;    // y[2s+1][c+256r]
        }
      }
    }
  }
}

// FUSED stages 2+3.  Block = (s, k1-quarter q), 512 threads = 8 waves (4m x 2n).
// GEMM1: C2[k2emb 512][k1l 64] = A2f x G2f  (both global, coalesced frag loads,
//   NO LDS, NO barriers).  Twiddle *WtT -> pack P frag-major into 64 KB LDS.
// ONE __syncthreads.  GEMM2: C3[cemb 512][k1l 64] = A3f x P(LDS ds_read_b128 at
//   base+lane*16: inherently conflict-free).  Epilogue *Tw(E+) -> H2f (u32).
// Contraction order (kc asc, ks asc) and all formulas verbatim from the
// unfused R7 path -> bit-identical output.
__global__ __launch_bounds__(512, 2) void dft_stage23R(
    const unsigned short* __restrict__ A2f,
    const unsigned short* __restrict__ A3f,
    const uint32_t* __restrict__ G2f,
    uint32_t* __restrict__ H2f,
    const float2* __restrict__ WtT,
    const float2* __restrict__ Tw) {
  __shared__ uint32_t Pl[16384];              // 64 KB: P frags (k1l 64 x k2 256)

  const int s = blockIdx.x >> 2;
  const int q = blockIdx.x & 3;

  const int tid = threadIdx.x;
  const int w = tid >> 6, lane = tid & 63;
  const int qlo = lane & 15, qhi = lane >> 4;
  const int wr = w >> 1, wc = w & 1;          // 4 m-wave-rows x 2 n-wave-cols

  const uint32_t* Bp = G2f + (size_t)s * 65536;

  floatx4 acc[8][2];
  #pragma unroll
  for (int i = 0; i < 8; ++i)
    #pragma unroll
    for (int j = 0; j < 2; ++j) acc[i][j] = (floatx4){0.f, 0.f, 0.f, 0.f};

  // ---- GEMM1 over c (K=512 shorts, kc 0..7, ks 0..1) ----
  #pragma unroll
  for (int kc = 0; kc < 8; ++kc) {
    #pragma unroll
    for (int ks = 0; ks < 2; ++ks) {
      short8 b[2];
      #pragma unroll
      for (int in = 0; in < 2; ++in) {
        const int n16 = q * 4 + wc * 2 + in;
        b[in] = *(const short8*)(Bp + (((kc * 16 + n16) * 2 + ks) * 256 + lane * 4));
      }
      #pragma unroll
      for (int im = 0; im < 8; ++im) {
        short8 a = *(const short8*)(A2f +
            (size_t)(((kc * 32 + wr * 8 + im) * 2 + ks) * 512 + lane * 8));
        #pragma unroll
        for (int in = 0; in < 2; ++in)
          acc[im][in] = __builtin_amdgcn_mfma_f32_16x16x32_bf16(
              a, b[in], acc[im][in], 0, 0, 0);
      }
    }
  }

  // ---- twiddle (*WtT) + pack -> P frag-major in LDS ----
  #pragma unroll
  for (int im = 0; im < 8; ++im) {
    #pragma unroll
    for (int in = 0; in < 2; ++in) {
      const int k1l = wc * 32 + in * 16 + qlo;
      const int k1g = q * 64 + k1l;
      const int n16l = wc * 2 + in;
      #pragma unroll
      for (int pp = 0; pp < 2; ++pp) {
        const int k2 = (wr * 8 + im) * 8 + qhi * 2 + pp;
        float re = acc[im][in][2*pp], iv = acc[im][in][2*pp+1];
        float2 wv = WtT[(k2 << 8) + k1g];
        float r2 = re * wv.x - iv * wv.y, i2 = re * wv.y + iv * wv.x;
        const int kcP = k2 >> 5, ksP = (k2 >> 4) & 1;
        const int qhiP = (k2 >> 2) & 3, jP = k2 & 3;
        Pl[((kcP * 4 + n16l) * 2 + ksP) * 256 + (qhiP * 16 + qlo) * 4 + jP] =
            packbf(r2, i2);
      }
    }
  }
  __syncthreads();                            // P complete & visible

  // ---- GEMM2 over k2 (K=512 emb shorts; B-frags from LDS, conflict-free) ----
  #pragma unroll
  for (int i = 0; i < 8; ++i)
    #pragma unroll
    for (int j = 0; j < 2; ++j) acc[i][j] = (floatx4){0.f, 0.f, 0.f, 0.f};

  #pragma unroll
  for (int kc = 0; kc < 8; ++kc) {
    #pragma unroll
    for (int ks = 0; ks < 2; ++ks) {
      short8 b[2];
      #pragma unroll
      for (int in = 0; in < 2; ++in)
        b[in] = *(const short8*)&Pl[((kc * 4 + wc * 2 + in) * 2 + ks) * 256 + lane * 4];
      #pragma unroll
      for (int im = 0; im < 8; ++im) {
        short8 a = *(const short8*)(A3f +
            (size_t)(((kc * 32 + wr * 8 + im) * 2 + ks) * 512 + lane * 8));
        #pragma unroll
        for (int in = 0; in < 2; ++in)
          acc[im][in] = __builtin_amdgcn_mfma_f32_16x16x32_bf16(
              a, b[in], acc[im][in], 0, 0, 0);
      }
    }
  }

  // ---- epilogue (*Tw, E+) -> H2f frag-major (rows=c, u32-cols=k1) ----
  uint32_t* Hp = H2f + (size_t)s * 65536;
  #pragma unroll
  for (int im = 0; im < 8; ++im) {
    #pragma unroll
    for (int in = 0; in < 2; ++in) {
      const int k1g = q * 64 + wc * 32 + in * 16 + qlo;
      const int kcH = (q << 1) | wc;          // k1g >> 5
      const int ksH = in;
      const int qhiH = qlo >> 2, jH = qlo & 3;
      #pragma unroll
      for (int pp = 0; pp < 2; ++pp) {
        const int c = (wr * 8 + im) * 8 + qhi * 2 + pp;
        float re = acc[im][in][2*pp], iv = acc[im][in][2*pp+1];
        float2 tw = Tw[(c << 8) + k1g];
        float r2 = re * tw.x - iv * tw.y, i2 = iv * tw.x + re * tw.y;
        Hp[((kcH * 16 + (c >> 4)) * 2 + ksH) * 256 +
           (qhiH * 16 + (c & 15)) * 4 + jH] = packbf(r2, i2);
      }
    }
  }
}

extern "C" void kernel_launch(void* const* d_in, const int* in_sizes, int n_in,
                              void* d_out, int out_size, void* d_ws, size_t ws_size,
                              hipStream_t stream) {
  const float* x = (const float*)d_in[0];     // [256][32768] fp32
  const float* filt = (const float*)d_in[1];  // [1][32768] fp32
  float* Y = (float*)d_out;                   // [256][32768] fp32

  char* ws = (char*)d_ws;
  unsigned short* A1 = (unsigned short*)(ws + 0);              // 256 KB
  unsigned short* A2 = (unsigned short*)(ws + 0x40000);        // 512 KB
  unsigned short* A3 = (unsigned short*)(ws + 0xC0000);        // 512 KB
  unsigned short* A4 = (unsigned short*)(ws + 0x140000);       // 256 KB
  float2* Gw  = (float2*)(ws + 0x180000);                      // 512 KB
  float2* WtT = (float2*)(ws + 0x200000);                      // 512 KB
  float2* Tw  = (float2*)(ws + 0x280000);                      // 512 KB
  uint32_t* Zp = (uint32_t*)(ws + (3u << 20));                 // 16 MB  [3,19)
  uint32_t* G2 = (uint32_t*)(ws + 19922944u);                  // 32 MB  [19,51)
  uint32_t* H2 = (uint32_t*)(ws + 53477376u);                  // 32 MB  [51,83)
                                                               // (must not alias
                                                               //  G2: fused reads
                                                               //  G2, writes H2)

  hipLaunchKernelGGL(prep_all, dim3(4608), dim3(256), 0, stream,
                     x, filt, A1, A2, A3, A4, Zp, Gw, Tw);
  hipLaunchKernelGGL(prep_wb, dim3(256), dim3(256), 0, stream, Gw, WtT);

  hipLaunchKernelGGL((dft_stageR<1, 4, 32>), dim3(1024), dim3(256), 0, stream,
                     A1, Zp, G2, (float*)nullptr, Tw);
  hipLaunchKernelGGL(dft_stage23R, dim3(512), dim3(512), 0, stream,
                     A2, A3, G2, H2, WtT, Tw);
  hipLaunchKernelGGL((dft_stageR<4, 8, 16>), dim3(512), dim3(256), 0, stream,
                     A4, H2, (uint32_t*)nullptr, Y, Tw);
}